// Round 12
// baseline (79.798 us; speedup 1.0000x reference)
//
#include <hip/hip_runtime.h>
#include <hip/hip_bf16.h>
#include <math.h>

// SupConLoss, B=4096 V=2 D=128, N=8192.
// loss = (1/N) [ sum_i log(sum_{j!=i} exp(n_i.n_j/T)) - 2*sum_b spos_b ]
// Round 12: R11 (global_load_lds m97-pattern, fragment-major nF, col-sums)
// with __launch_bounds__(256,4): grid is 1024 blocks = 4/CU, but (256,3)
// allowed only 3 co-resident -> two dispatch generations (3/CU then 1/CU),
// a ~33% tail on a latency-bound kernel. 4 waves/SIMD needs <=128 VGPRs;
// R11 live state ~116 (afrag 64 + acc 32 + misc). Spill tripwire: WRITE_SIZE.

constexpr int   Bsz   = 4096;
constexpr int   Nrows = 8192;
constexpr int   Dd    = 128;
constexpr float TEMPf = 0.07f;
constexpr float EPSN  = 1e-8f;
constexpr float SCALE = 1.4426950408889634f / 0.07f;  // log2(e)/T
constexpr float LN2   = 0.6931471805599453f;

constexpr int CHUNKS     = 32;                 // col chunks (grid.x)
constexpr int CHUNK_COLS = Nrows / CHUNKS;     // 256
constexpr int TILES      = CHUNK_COLS / 32;    // 8 tiles of 32 cols
constexpr int ROWS_BLK   = 256;                // rows per block (4 waves x 64)
constexpr int YG         = Nrows / ROWS_BLK;   // 32 (grid.y)
constexpr int PREPBLKS   = Bsz / 4;            // 1024

typedef __attribute__((ext_vector_type(8)))  short bf16x8;   // 8 bf16 = 4 VGPRs
typedef __attribute__((ext_vector_type(16))) float floatx16; // MFMA 32x32 C/D

// Fragment-major n: row r = g*32+lo stores its 256 B as pieces at
// g*8192 + kc*1024 + hi*512 + lo*16. Wave fragment load (g,kc) =
// base + g*8192 + kc*1024 + lane*16 — one coalesced 1 KB access, and
// global_load_lds placement (lds_base + lane*16) reproduces it in LDS.

// ws layout (bytes):
//   0x000000  nF   fragment-major bf16 n   2 MB
//   0x200000  partial f32[32][8192]        1 MB   (col sums per row-group)
//   0x300000  sposPart f32[1024]           4 KB
constexpr size_t OFF_PART = 0x200000;
constexpr size_t OFF_SPOS = 0x300000;

__device__ __forceinline__ void gld_lds16(const void* g, void* l) {
    __builtin_amdgcn_global_load_lds(
        (const __attribute__((address_space(1))) void*)g,
        (__attribute__((address_space(3))) void*)l, 16, 0, 0);
}

// ------------- prep: normalize both views -> nF + per-block spos sums ----------
__global__ void prep_k(const float* __restrict__ f,
                       char* __restrict__ nF,
                       float* __restrict__ sposPart,
                       float* __restrict__ out) {
    __shared__ float sred[4];
    int tid  = threadIdx.x;
    int wid  = tid >> 6;
    int lane = tid & 63;
    int b    = blockIdx.x * 4 + wid;
    if (blockIdx.x == 0 && tid == 0) out[0] = 0.f;   // final_k accumulates

    const float* s0 = f + (size_t)(b * 2) * Dd;       // features[b, 0, :]
    float2 x = *(const float2*)(s0 + lane * 2);       // view 0
    float2 y = *(const float2*)(s0 + Dd + lane * 2);  // view 1
    float ss0 = x.x * x.x + x.y * x.y;
    float ss1 = y.x * y.x + y.y * y.y;
    float dt  = x.x * y.x + x.y * y.y;
    #pragma unroll
    for (int off = 32; off; off >>= 1) {
        ss0 += __shfl_xor(ss0, off);
        ss1 += __shfl_xor(ss1, off);
        dt  += __shfl_xor(dt,  off);
    }
    float inv0 = 1.0f / fmaxf(sqrtf(ss0), EPSN);
    float inv1 = 1.0f / fmaxf(sqrtf(ss1), EPSN);

    // lane holds k = 2*lane..2*lane+1 -> piece (kc=lane>>3, hi=(lane>>2)&1),
    // byte offset inside piece = (lane&3)*4
    size_t poff = (size_t)(lane >> 3) * 1024 + ((lane >> 2) & 1) * 512
                + (lane & 3) * 4;

    __hip_bfloat162 h;
    h.x = __float2bfloat16(x.x * inv0);
    h.y = __float2bfloat16(x.y * inv0);
    *(__hip_bfloat162*)(nF + (size_t)(b >> 5) * 8192 + (b & 31) * 16 + poff) = h;
    int r1 = Bsz + b;
    h.x = __float2bfloat16(y.x * inv1);
    h.y = __float2bfloat16(y.y * inv1);
    *(__hip_bfloat162*)(nF + (size_t)(r1 >> 5) * 8192 + (r1 & 31) * 16 + poff) = h;

    if (lane == 0) sred[wid] = dt * inv0 * inv1 / TEMPf;
    __syncthreads();
    if (tid == 0) sposPart[blockIdx.x] = sred[0] + sred[1] + sred[2] + sred[3];
}

// ------------- main: async-LDS GEMM + exp2 + column sums -----------------------
// Grid (32 chunks, 32 row-groups) = 1024 blocks = 4/CU, ALL co-resident.
// Wave: 64 rows x 32-col tiles; B tile (8 KB) double-buffered via
// global_load_lds (2 instrs/wave/tile); one barrier per tile.
// Column sums (== row sums by symmetry of exp(S)): one scalar/lane/tile.
__global__ __launch_bounds__(256, 4)
void main_k(const char* __restrict__ nF, float* __restrict__ partial) {
    __shared__ char  bufs[2][8192];
    __shared__ float colred[4][256];
    const int tid  = threadIdx.x;
    const int wid  = tid >> 6;
    const int lane = tid & 63;
    const int lo   = lane & 31;
    const int hi   = lane >> 5;
    const int gy   = blockIdx.y;
    const int rbase = gy * ROWS_BLK + wid * 64;          // wave's 64 rows
    const int cbase = blockIdx.x * CHUNK_COLS;           // 256-aligned
    const int cg0   = cbase >> 5;                        // first col group

    // A fragments: two 32-row groups, 8 coalesced 1 KB loads each (64 VGPRs)
    bf16x8 afrag[2][8];
    #pragma unroll
    for (int s = 0; s < 2; s++) {
        const char* ag = nF + (size_t)((rbase + s * 32) >> 5) * 8192 + lane * 16;
        #pragma unroll
        for (int kc = 0; kc < 8; kc++)
            afrag[s][kc] = *(const bf16x8*)(ag + kc * 1024);
    }

    // stage tile 0 (each wave DMAs fragments kc = 2*wid, 2*wid+1)
    {
        const char* g0 = nF + (size_t)cg0 * 8192;
        int kc = wid * 2;
        gld_lds16(g0 + kc * 1024 + lane * 16,       &bufs[0][kc * 1024]);
        gld_lds16(g0 + (kc + 1) * 1024 + lane * 16, &bufs[0][(kc + 1) * 1024]);
    }

    floatx16 zero = {};

    #pragma unroll 1
    for (int t = 0; t < TILES; t++) {
        // barrier: tile t DMA drained (compiler emits vmcnt(0) before
        // s_barrier) + all waves done reading the buffer staged next
        __syncthreads();
        if (t + 1 < TILES) {
            const char* gn = nF + (size_t)(cg0 + t + 1) * 8192;
            char* dst = bufs[(t + 1) & 1];
            int kc = wid * 2;
            gld_lds16(gn + kc * 1024 + lane * 16,       dst + kc * 1024);
            gld_lds16(gn + (kc + 1) * 1024 + lane * 16, dst + (kc + 1) * 1024);
        }

        const char* buf = bufs[t & 1];
        floatx16 acc0 = zero, acc1 = zero;
        #pragma unroll
        for (int kc = 0; kc < 8; kc++) {
            bf16x8 bf = *(const bf16x8*)&buf[kc * 1024 + lane * 16];
            acc0 = __builtin_amdgcn_mfma_f32_32x32x16_bf16(afrag[0][kc], bf, acc0, 0, 0, 0);
            acc1 = __builtin_amdgcn_mfma_f32_32x32x16_bf16(afrag[1][kc], bf, acc1, 0, 0, 0);
        }

        // epilogue: exp2, diag mask (wave-uniform branch), COLUMN sums
        const int cb32 = cbase + t * 32;
        float cs = 0.f;
        #pragma unroll
        for (int s = 0; s < 2; s++) {
            const floatx16& acc = s ? acc1 : acc0;
            if (cb32 == rbase + s * 32) {     // taken <=1 of 16 (s,t) combos
                #pragma unroll
                for (int r = 0; r < 16; r++) {
                    float e = __builtin_amdgcn_exp2f(acc[r] * SCALE);
                    // C/D layout: col=lo, row_local=(r&3)+8*(r>>2)+4*hi
                    if (lo == ((r & 3) + 8 * (r >> 2) + 4 * hi)) e = 0.f;
                    cs += e;
                }
            } else {
                #pragma unroll
                for (int r = 0; r < 16; r++)
                    cs += __builtin_amdgcn_exp2f(acc[r] * SCALE);
            }
        }
        cs += __shfl_xor(cs, 32);             // fold the two row-half lanes
        if (hi == 0) colred[wid][t * 32 + lo] = cs;
    }

    __syncthreads();
    // cross-wave: block's col sums over its 256-row stripe, coalesced store
    float v = colred[0][tid] + colred[1][tid] + colred[2][tid] + colred[3][tid];
    partial[(size_t)gy * Nrows + cbase + tid] = v;
}

// ------------- finalize: 32 blocks; atomicAdd the scalar -----------------------
// se[r] = sum_gy partial[gy][r]  (column sum == row sum of exp matrix)
__global__ __launch_bounds__(256)
void final_k(const float* __restrict__ partial, const float* __restrict__ sposPart,
             float* __restrict__ out) {
    __shared__ float red[4];
    int tid = threadIdx.x;
    int r = blockIdx.x * 256 + tid;
    float se = 0.f;
    #pragma unroll
    for (int p = 0; p < YG; p++) se += partial[(size_t)p * Nrows + r];
    float acc = __builtin_amdgcn_logf(se) * LN2;   // v_log_f32 is log2
    if (tid < 32) acc -= 2.f * sposPart[blockIdx.x * 32 + tid];
    #pragma unroll
    for (int off = 32; off; off >>= 1) acc += __shfl_xor(acc, off);
    if ((tid & 63) == 0) red[tid >> 6] = acc;
    __syncthreads();
    if (tid == 0)
        atomicAdd(out, (red[0] + red[1] + red[2] + red[3]) / (float)Nrows);
}

extern "C" void kernel_launch(void* const* d_in, const int* in_sizes, int n_in,
                              void* d_out, int out_size, void* d_ws, size_t ws_size,
                              hipStream_t stream) {
    const float* f = (const float*)d_in[0];
    char* ws = (char*)d_ws;
    char* nF        = ws;
    float* partial  = (float*)(ws + OFF_PART);
    float* sposPart = (float*)(ws + OFF_SPOS);

    prep_k<<<PREPBLKS, 256, 0, stream>>>(f, nF, sposPart, (float*)d_out);
    dim3 grid(CHUNKS, YG);
    main_k<<<grid, 256, 0, stream>>>(nF, partial);
    final_k<<<Nrows / 256, 256, 0, stream>>>(partial, sposPart, (float*)d_out);
}